// Round 1
// baseline (162.289 us; speedup 1.0000x reference)
//
#include <hip/hip_runtime.h>
#include <hip/hip_bf16.h>

// Problem constants
constexpr int NN    = 4096;     // nodes
constexpr int EE    = 131072;   // edges
constexpr int IN_F  = 256;
constexpr int OUT_F = 64;
constexpr int HH    = 8;
constexpr int HF    = OUT_F * HH;   // 512

// ---------------------------------------------------------------------------
// K1: Wh = x @ W   (4096x256 @ 256x512, fp32)
// tile 128x64, 256 threads, 8x4 microtile, BK=32
// ---------------------------------------------------------------------------
#define BM 128
#define BN 64
#define BKK 32

__global__ __launch_bounds__(256) void gemm_xw(const float* __restrict__ x,
                                               const float* __restrict__ W,
                                               float* __restrict__ Wh) {
    __shared__ float As[BKK][BM + 4];   // 32 x 132 (pad keeps f4 align, spreads banks)
    __shared__ float Bs[BKK][BN + 4];   // 32 x 68
    int t  = threadIdx.x;
    int tx = t & 15;    // n dim, 4 cols
    int ty = t >> 4;    // m dim, 8 rows
    int m0 = blockIdx.x * BM;
    int n0 = blockIdx.y * BN;
    float acc[8][4] = {};

    for (int k0 = 0; k0 < IN_F; k0 += BKK) {
        // A tile: 128x32 = 1024 float4 / 256 thr = 4 each; store transposed As[k][m]
#pragma unroll
        for (int i = 0; i < 4; ++i) {
            int flat = i * 256 + t;       // 0..1023
            int row  = flat >> 3;         // 0..127
            int c4   = flat & 7;          // 0..7
            float4 v = *(const float4*)(x + (size_t)(m0 + row) * IN_F + k0 + c4 * 4);
            As[c4 * 4 + 0][row] = v.x;
            As[c4 * 4 + 1][row] = v.y;
            As[c4 * 4 + 2][row] = v.z;
            As[c4 * 4 + 3][row] = v.w;
        }
        // B tile: 32x64 = 512 float4 / 256 thr = 2 each
#pragma unroll
        for (int i = 0; i < 2; ++i) {
            int flat = i * 256 + t;       // 0..511
            int row  = flat >> 4;         // 0..31
            int c4   = flat & 15;         // 0..15
            *(float4*)(&Bs[row][c4 * 4]) =
                *(const float4*)(W + (size_t)(k0 + row) * HF + n0 + c4 * 4);
        }
        __syncthreads();
#pragma unroll
        for (int k = 0; k < BKK; ++k) {
            float4 a0 = *(const float4*)(&As[k][ty * 8]);
            float4 a1 = *(const float4*)(&As[k][ty * 8 + 4]);
            float4 b0 = *(const float4*)(&Bs[k][tx * 4]);
            float a[8] = {a0.x, a0.y, a0.z, a0.w, a1.x, a1.y, a1.z, a1.w};
            float b[4] = {b0.x, b0.y, b0.z, b0.w};
#pragma unroll
            for (int ii = 0; ii < 8; ++ii)
#pragma unroll
                for (int jj = 0; jj < 4; ++jj)
                    acc[ii][jj] += a[ii] * b[jj];
        }
        __syncthreads();
    }
#pragma unroll
    for (int ii = 0; ii < 8; ++ii) {
        float4 v = {acc[ii][0], acc[ii][1], acc[ii][2], acc[ii][3]};
        *(float4*)(Wh + (size_t)(m0 + ty * 8 + ii) * HF + n0 + tx * 4) = v;
    }
}

// ---------------------------------------------------------------------------
// K2a: alpha_src[n,h] = Wh[n,h,:]·a1 ; alpha_dst[n,h] = Wh[n,h,:]·a2
// one wave per node
// ---------------------------------------------------------------------------
__global__ __launch_bounds__(64) void alpha_kernel(const float* __restrict__ Wh,
                                                   const float* __restrict__ a,
                                                   float* __restrict__ asrc,
                                                   float* __restrict__ adst) {
    int i = blockIdx.x;
    int l = threadIdx.x;          // 0..63
    float a1 = a[l];
    float a2 = a[OUT_F + l];
    const float* row = Wh + (size_t)i * HF;
#pragma unroll
    for (int h = 0; h < HH; ++h) {
        float w  = row[h * OUT_F + l];
        float s1 = w * a1;
        float s2 = w * a2;
#pragma unroll
        for (int d = 1; d < 64; d <<= 1) {
            s1 += __shfl_xor(s1, d);
            s2 += __shfl_xor(s2, d);
        }
        if (l == 0) {
            asrc[i * HH + h] = s1;
            adst[i * HH + h] = s2;
        }
    }
}

// ---------------------------------------------------------------------------
// K2b: S[c] = sum_n Wh[n][c]   (column sums, 512 cols)
// 128 blocks x 32 rows each, atomicAdd partials
// ---------------------------------------------------------------------------
__global__ __launch_bounds__(256) void colsum_kernel(const float* __restrict__ Wh,
                                                     float* __restrict__ S) {
    int b = blockIdx.x;       // 0..127
    int t = threadIdx.x;      // 0..255
    float s0 = 0.f, s1 = 0.f;
    for (int r = 0; r < 32; ++r) {
        const float* row = Wh + (size_t)(b * 32 + r) * HF;
        s0 += row[t];
        s1 += row[t + 256];
    }
    atomicAdd(&S[t], s0);
    atomicAdd(&S[t + 256], s1);
}

// ---------------------------------------------------------------------------
// K3: per-src edge counts (duplicates included — capacity only)
// ---------------------------------------------------------------------------
__global__ __launch_bounds__(256) void count_edges(const int* __restrict__ src,
                                                   int* __restrict__ cnt) {
    int e = blockIdx.x * 256 + threadIdx.x;
    if (e < EE) atomicAdd(&cnt[src[e]], 1);
}

// ---------------------------------------------------------------------------
// K4: exclusive scan of 4096 counts -> rowstart, cursor
// one block, 1024 threads, 4 elems/thread, wave-shuffle scan
// ---------------------------------------------------------------------------
__global__ __launch_bounds__(1024) void scan_kernel(const int* __restrict__ cnt,
                                                    int* __restrict__ rowstart,
                                                    int* __restrict__ cursor) {
    __shared__ int wsum[16];
    __shared__ int wbase[16];
    int t    = threadIdx.x;
    int lane = t & 63, wid = t >> 6;
    int4 c = ((const int4*)cnt)[t];
    int s  = c.x + c.y + c.z + c.w;
    int v  = s;
#pragma unroll
    for (int d = 1; d < 64; d <<= 1) {
        int u = __shfl_up(v, d);
        if (lane >= d) v += u;
    }
    if (lane == 63) wsum[wid] = v;
    __syncthreads();
    if (wid == 0 && lane < 16) {
        int w  = wsum[lane];
        int vv = w;
#pragma unroll
        for (int d = 1; d < 16; d <<= 1) {
            int u = __shfl_up(vv, d);
            if (lane >= d) vv += u;
        }
        wbase[lane] = vv - w;   // exclusive
    }
    __syncthreads();
    int excl = wbase[wid] + v - s;   // exclusive prefix of this thread's 4 slots
    int4 r;
    r.x = excl;
    r.y = excl + c.x;
    r.z = r.y + c.y;
    r.w = r.z + c.z;
    ((int4*)rowstart)[t] = r;
    ((int4*)cursor)[t]   = r;
}

// ---------------------------------------------------------------------------
// K5: scatter edges into CSR with exact dedup via bitmap atomicOr.
// Duplicate (s,d) pairs carry identical values under .set() semantics,
// so keeping exactly one is exact.
// ---------------------------------------------------------------------------
__global__ __launch_bounds__(256) void scatter_edges(const int* __restrict__ src,
                                                     const int* __restrict__ dst,
                                                     unsigned int* __restrict__ bitmap,
                                                     int* __restrict__ cursor,
                                                     int* __restrict__ csr_dst) {
    int e = blockIdx.x * 256 + threadIdx.x;
    if (e >= EE) return;
    int s = src[e], d = dst[e];
    unsigned int bitidx = (unsigned int)s * NN + (unsigned int)d;
    unsigned int word   = bitidx >> 5;
    unsigned int mask   = 1u << (bitidx & 31);
    unsigned int old    = atomicOr(&bitmap[word], mask);
    if (!(old & mask)) {
        int pos = atomicAdd(&cursor[s], 1);
        csr_dst[pos] = d;
    }
}

// ---------------------------------------------------------------------------
// K6: per-node aggregation.
// out[i,h,f] = (S[h,f] + sum_edges (exp(e)-1)*Wh[m,h,f]) / (N + sum_edges (exp(e)-1))
// 1 block / node, 512 threads, thread = (h,f). Wh row reads are coalesced 2KB.
// ---------------------------------------------------------------------------
__global__ __launch_bounds__(512) void aggregate_kernel(const float* __restrict__ Wh,
                                                        const float* __restrict__ asrc,
                                                        const float* __restrict__ adst,
                                                        const float* __restrict__ S,
                                                        const int* __restrict__ rowstart,
                                                        const int* __restrict__ cursor,
                                                        const int* __restrict__ csr_dst,
                                                        float* __restrict__ out) {
    __shared__ int mbuf[128];
    int i = blockIdx.x;
    int t = threadIdx.x;         // 0..511
    int h = t >> 6;              // head
    float as    = asrc[i * HH + h];
    int   start = rowstart[i];
    int   cnt   = cursor[i] - start;   // unique degree
    float acc = 0.f, z = 0.f;

    for (int j0 = 0; j0 < cnt; j0 += 128) {
        int chunk = min(128, cnt - j0);
        if (t < chunk) mbuf[t] = csr_dst[start + j0 + t];
        __syncthreads();
        for (int j = 0; j < chunk; ++j) {
            int   m = mbuf[j];
            float e = as + adst[m * HH + h];
            e = (e > 0.f) ? e : 0.2f * e;           // leaky_relu(., 0.2)
            float w = __expf(e) - 1.f;
            z   += w;
            acc += w * Wh[(size_t)m * HF + t];
        }
        __syncthreads();
    }
    out[(size_t)i * HF + t] = (S[t] + acc) / ((float)NN + z);
}

// ---------------------------------------------------------------------------
// launcher
// ---------------------------------------------------------------------------
extern "C" void kernel_launch(void* const* d_in, const int* in_sizes, int n_in,
                              void* d_out, int out_size, void* d_ws, size_t ws_size,
                              hipStream_t stream) {
    const float* x  = (const float*)d_in[0];
    const float* W  = (const float*)d_in[1];
    const float* a  = (const float*)d_in[2];
    const int*   ei = (const int*)d_in[3];
    const int* src = ei;
    const int* dst = ei + EE;
    float* out = (float*)d_out;

    // workspace layout (bytes)
    char* ws = (char*)d_ws;
    float* Wh       = (float*)(ws + 0);               // 8,388,608
    float* asrc     = (float*)(ws + 8388608);         // 131,072
    float* adst     = (float*)(ws + 8519680);         // 131,072
    int*   rowstart = (int*)  (ws + 8650752);         // 16,448
    int*   cursor   = (int*)  (ws + 8667200);         // 16,448
    int*   csr_dst  = (int*)  (ws + 8683648);         // 524,288
    float* S        = (float*)(ws + 9207936);         // 2,048
    int*   cnt      = (int*)  (ws + 9209984);         // 16,384
    unsigned int* bitmap = (unsigned int*)(ws + 9226368); // 2,097,152

    // zero S + cnt + bitmap in one contiguous memset (harness poisons ws)
    hipMemsetAsync(ws + 9207936, 0, 2048 + 16384 + 2097152, stream);

    // K1: Wh = x @ W
    gemm_xw<<<dim3(NN / BM, HF / BN), 256, 0, stream>>>(x, W, Wh);

    // K2: alphas + column sums
    alpha_kernel<<<NN, 64, 0, stream>>>(Wh, a, asrc, adst);
    colsum_kernel<<<NN / 32, 256, 0, stream>>>(Wh, S);

    // K3..K5: CSR build with exact dedup
    count_edges<<<EE / 256, 256, 0, stream>>>(src, cnt);
    scan_kernel<<<1, 1024, 0, stream>>>(cnt, rowstart, cursor);
    scatter_edges<<<EE / 256, 256, 0, stream>>>(src, dst, bitmap, cursor, csr_dst);

    // K6: aggregation
    aggregate_kernel<<<NN, 512, 0, stream>>>(Wh, asrc, adst, S, rowstart, cursor,
                                             csr_dst, out);
}

// Round 4
// 136.711 us; speedup vs baseline: 1.1871x; 1.1871x over previous
//
#include <hip/hip_runtime.h>
#include <hip/hip_bf16.h>

// Problem constants
constexpr int NN    = 4096;     // nodes
constexpr int EE    = 131072;   // edges
constexpr int IN_F  = 256;
constexpr int OUT_F = 64;
constexpr int HH    = 8;
constexpr int HF    = OUT_F * HH;   // 512
constexpr int CAP   = 128;          // CSR capacity per node (mean deg 32, 17-sigma safe)

// ---------------------------------------------------------------------------
// K1: fused  Wh = x @ W  +  alpha_src/dst  +  column-sums S
// tile 64x64, 256 threads, 4x4 microtile, BK=32.
// Each (m0,n0) tile covers ONE full head (OUT_F=64) -> alpha dot products are
// block-local: 16-lane shuffle reduce, direct store (no atomics).
// ---------------------------------------------------------------------------
#define TM 64
#define TN 64
#define TK 32

__global__ __launch_bounds__(256) void gemm_fused(const float* __restrict__ x,
                                                  const float* __restrict__ W,
                                                  const float* __restrict__ a,
                                                  float* __restrict__ Wh,
                                                  float* __restrict__ asrc,
                                                  float* __restrict__ adst,
                                                  float* __restrict__ S) {
    __shared__ float As[TK][TM + 4];   // transposed A tile
    __shared__ float Bs[TK][TN + 4];
    __shared__ float Scol[TN];
    int t  = threadIdx.x;
    int tx = t & 15;    // 4 cols each
    int ty = t >> 4;    // 4 rows each
    int m0 = blockIdx.x * TM;
    int n0 = blockIdx.y * TN;
    float acc[4][4] = {};

    for (int k0 = 0; k0 < IN_F; k0 += TK) {
        // A tile 64x32 = 512 float4, 2 per thread; store transposed As[k][m]
#pragma unroll
        for (int i = 0; i < 2; ++i) {
            int flat = i * 256 + t;       // 0..511
            int row  = flat >> 3;         // 0..63
            int c4   = flat & 7;          // 0..7
            float4 v = *(const float4*)(x + (size_t)(m0 + row) * IN_F + k0 + c4 * 4);
            As[c4 * 4 + 0][row] = v.x;
            As[c4 * 4 + 1][row] = v.y;
            As[c4 * 4 + 2][row] = v.z;
            As[c4 * 4 + 3][row] = v.w;
        }
        // B tile 32x64 = 512 float4, 2 per thread
#pragma unroll
        for (int i = 0; i < 2; ++i) {
            int flat = i * 256 + t;       // 0..511
            int row  = flat >> 4;         // 0..31
            int c4   = flat & 15;         // 0..15
            *(float4*)(&Bs[row][c4 * 4]) =
                *(const float4*)(W + (size_t)(k0 + row) * HF + n0 + c4 * 4);
        }
        __syncthreads();
#pragma unroll
        for (int k = 0; k < TK; ++k) {
            float4 a4 = *(const float4*)(&As[k][ty * 4]);
            float4 b4 = *(const float4*)(&Bs[k][tx * 4]);
            float av[4] = {a4.x, a4.y, a4.z, a4.w};
            float bv[4] = {b4.x, b4.y, b4.z, b4.w};
#pragma unroll
            for (int ii = 0; ii < 4; ++ii)
#pragma unroll
                for (int jj = 0; jj < 4; ++jj)
                    acc[ii][jj] += av[ii] * bv[jj];
        }
        __syncthreads();
    }

    // write Wh
#pragma unroll
    for (int ii = 0; ii < 4; ++ii) {
        float4 v = {acc[ii][0], acc[ii][1], acc[ii][2], acc[ii][3]};
        *(float4*)(Wh + (size_t)(m0 + ty * 4 + ii) * HF + n0 + tx * 4) = v;
    }

    // ---- fused alpha epilogue: this tile covers head h fully ----
    int h = n0 >> 6;                 // head index
    float a1v[4], a2v[4];
#pragma unroll
    for (int jj = 0; jj < 4; ++jj) {
        int f = tx * 4 + jj;         // feature within head
        a1v[jj] = a[f];
        a2v[jj] = a[OUT_F + f];
    }
#pragma unroll
    for (int ii = 0; ii < 4; ++ii) {
        float p1 = 0.f, p2 = 0.f;
#pragma unroll
        for (int jj = 0; jj < 4; ++jj) {
            p1 += acc[ii][jj] * a1v[jj];
            p2 += acc[ii][jj] * a2v[jj];
        }
        // reduce across the 16 tx lanes (contiguous within a wave)
#pragma unroll
        for (int mask = 1; mask < 16; mask <<= 1) {
            p1 += __shfl_xor(p1, mask);
            p2 += __shfl_xor(p2, mask);
        }
        if (tx == 0) {
            int node = m0 + ty * 4 + ii;
            asrc[node * HH + h] = p1;
            adst[node * HH + h] = p2;
        }
    }

    // ---- fused column-sum epilogue ----
    if (t < TN) Scol[t] = 0.f;
    __syncthreads();
#pragma unroll
    for (int jj = 0; jj < 4; ++jj) {
        float cs = acc[0][jj] + acc[1][jj] + acc[2][jj] + acc[3][jj];
        atomicAdd(&Scol[tx * 4 + jj], cs);
    }
    __syncthreads();
    if (t < TN) atomicAdd(&S[n0 + t], Scol[t]);
}

// ---------------------------------------------------------------------------
// K2: scatter edges into fixed-capacity CSR with exact dedup (bitmap atomicOr).
// Duplicate (s,d) pairs carry identical values under .set() semantics.
// ---------------------------------------------------------------------------
__global__ __launch_bounds__(256) void scatter_edges(const int* __restrict__ src,
                                                     const int* __restrict__ dst,
                                                     unsigned int* __restrict__ bitmap,
                                                     int* __restrict__ cnt,
                                                     int* __restrict__ csr_dst) {
    int e = blockIdx.x * 256 + threadIdx.x;
    if (e >= EE) return;
    int s = src[e], d = dst[e];
    unsigned int bitidx = ((unsigned int)s << 12) | (unsigned int)d;
    unsigned int word   = bitidx >> 5;
    unsigned int mask   = 1u << (bitidx & 31);
    unsigned int old    = atomicOr(&bitmap[word], mask);
    if (!(old & mask)) {
        int pos = atomicAdd(&cnt[s], 1);
        csr_dst[(s << 7) + pos] = d;
    }
}

// ---------------------------------------------------------------------------
// K3: per-node aggregation, 4 edges in flight.
// out[i,h,f] = (S[h,f] + sum_e (exp(e)-1)*Wh[m,h,f]) / (N + sum_e (exp(e)-1))
// 512 threads = 4 groups x 128; group g owns edges g, g+4, ... ; each lane
// reads float4 of the Wh row (16B/lane). Cross-group reduce via LDS.
// One-ahead prefetch of BOTH the next edge index and its adst value keeps the
// gather chain (row[j] -> adst[m] -> expf -> FMA) pipelined across iterations.
// ---------------------------------------------------------------------------
__global__ __launch_bounds__(512) void aggregate_kernel(const float* __restrict__ Wh,
                                                        const float* __restrict__ asrc,
                                                        const float* __restrict__ adst,
                                                        const float* __restrict__ S,
                                                        const int* __restrict__ cnt,
                                                        const int* __restrict__ csr_dst,
                                                        float* __restrict__ out) {
    __shared__ float red[4][HF];     // 8 KB
    __shared__ float zred[4][HH];
    int i = blockIdx.x;
    int t = threadIdx.x;             // 0..511
    int g = t >> 7;                  // edge group 0..3
    int r = t & 127;                 // lane within group; covers floats r*4..r*4+3
    int h = r >> 4;                  // head of this float4 slice
    float as  = asrc[i * HH + h];
    int  deg  = cnt[i];
    const int* row = csr_dst + (i << 7);

    float4 acc = {0.f, 0.f, 0.f, 0.f};
    float  z   = 0.f;

    int j = g;
    int   m  = (j < deg) ? row[j] : 0;
    float ad = (j < deg) ? adst[m * HH + h] : 0.f;
    while (j < deg) {
        int jn = j + 4;
        int   mn  = (jn < deg) ? row[jn] : 0;            // one-ahead index prefetch
        float adn = (jn < deg) ? adst[mn * HH + h] : 0.f; // one-ahead adst prefetch
        float e = as + ad;
        e = (e > 0.f) ? e : 0.2f * e;           // leaky_relu(., 0.2)
        float w = __expf(e) - 1.f;
        float4 v = *(const float4*)(Wh + ((size_t)m << 9) + (r << 2));
        acc.x += w * v.x;
        acc.y += w * v.y;
        acc.z += w * v.z;
        acc.w += w * v.w;
        if (!(r & 15)) z += w;                  // one rep per (head, group)
        m  = mn;
        ad = adn;
        j  = jn;
    }

    *(float4*)(&red[g][r << 2]) = acc;
    if (!(r & 15)) zred[g][h] = z;
    __syncthreads();

    float tot = red[0][t] + red[1][t] + red[2][t] + red[3][t] + S[t];
    int   th  = t >> 6;              // head of output element t
    float zz  = (float)NN + zred[0][th] + zred[1][th] + zred[2][th] + zred[3][th];
    out[((size_t)i << 9) + t] = tot / zz;
}

// ---------------------------------------------------------------------------
// launcher
// ---------------------------------------------------------------------------
extern "C" void kernel_launch(void* const* d_in, const int* in_sizes, int n_in,
                              void* d_out, int out_size, void* d_ws, size_t ws_size,
                              hipStream_t stream) {
    const float* x  = (const float*)d_in[0];
    const float* W  = (const float*)d_in[1];
    const float* a  = (const float*)d_in[2];
    const int*   ei = (const int*)d_in[3];
    const int* src = ei;
    const int* dst = ei + EE;
    float* out = (float*)d_out;

    // workspace layout (bytes)
    char* ws = (char*)d_ws;
    float* Wh       = (float*)(ws + 0);               // 8,388,608
    float* asrc     = (float*)(ws + 8388608);         // 131,072
    float* adst     = (float*)(ws + 8519680);         // 131,072
    int*   csr_dst  = (int*)  (ws + 8650752);         // 4096*128*4 = 2,097,152
    float* S        = (float*)(ws + 10747904);        // 2,048
    int*   cnt      = (int*)  (ws + 10749952);        // 16,384
    unsigned int* bitmap = (unsigned int*)(ws + 10766336); // 2,097,152

    // zero S + cnt + bitmap in one contiguous memset
    hipMemsetAsync(ws + 10747904, 0, 2048 + 16384 + 2097152, stream);

    // K1: fused GEMM + alphas + column sums
    gemm_fused<<<dim3(NN / TM, HF / TN), 256, 0, stream>>>(x, W, a, Wh, asrc, adst, S);

    // K2: CSR build with exact dedup
    scatter_edges<<<EE / 256, 256, 0, stream>>>(src, dst, bitmap, cnt, csr_dst);

    // K3: aggregation
    aggregate_kernel<<<NN, 512, 0, stream>>>(Wh, asrc, adst, S, cnt, csr_dst, out);
}

// Round 5
// 130.761 us; speedup vs baseline: 1.2411x; 1.0455x over previous
//
#include <hip/hip_runtime.h>
#include <hip/hip_bf16.h>

// Problem constants
constexpr int NN    = 4096;     // nodes
constexpr int EE    = 131072;   // edges
constexpr int IN_F  = 256;
constexpr int OUT_F = 64;
constexpr int HH    = 8;
constexpr int HF    = OUT_F * HH;   // 512
constexpr int CAP   = 128;          // CSR capacity per node (mean deg 32, max ~54)

// f32 -> bf16 round-to-nearest-even (bit-exact with standard bf16 RN)
__device__ __forceinline__ unsigned short f2b(float f) {
    unsigned int u = __float_as_uint(f);
    u = u + 0x7FFFu + ((u >> 16) & 1u);
    return (unsigned short)(u >> 16);
}
// bf16 (as u16) -> f32 is exact: shift into high bits
__device__ __forceinline__ float b2f(unsigned int lo16) {
    return __uint_as_float(lo16 << 16);
}

// ---------------------------------------------------------------------------
// K1: fused  Whb(bf16) = x @ W  +  alpha_src/dst  +  column-sums S(fp32)
// tile 64x64, 256 threads, 4x4 microtile, BK=32, register double-buffer.
// Each (m0,n0) tile covers ONE full head -> alpha dots are block-local.
// Wh is stored bf16 ONLY (consumed solely by the aggregate gather); alphas
// and S are computed from fp32 accumulators so attention weights stay exact.
// ---------------------------------------------------------------------------
#define TM 64
#define TN 64
#define TK 32

__global__ __launch_bounds__(256) void gemm_fused(const float* __restrict__ x,
                                                  const float* __restrict__ W,
                                                  const float* __restrict__ a,
                                                  unsigned short* __restrict__ Whb,
                                                  float* __restrict__ asrc,
                                                  float* __restrict__ adst,
                                                  float* __restrict__ S) {
    __shared__ float As[TK][TM + 4];   // transposed A tile
    __shared__ float Bs[TK][TN + 4];
    __shared__ float Scol[TN];
    int t  = threadIdx.x;
    int tx = t & 15;    // 4 cols each
    int ty = t >> 4;    // 4 rows each
    int m0 = blockIdx.x * TM;
    int n0 = blockIdx.y * TN;
    float acc[4][4] = {};

    // prefetch registers (A: 2 float4, B: 2 float4 per thread)
    float4 pa[2], pb[2];
    {
        int k0 = 0;
#pragma unroll
        for (int i = 0; i < 2; ++i) {
            int flat = i * 256 + t, row = flat >> 3, c4 = flat & 7;
            pa[i] = *(const float4*)(x + (size_t)(m0 + row) * IN_F + k0 + c4 * 4);
        }
#pragma unroll
        for (int i = 0; i < 2; ++i) {
            int flat = i * 256 + t, row = flat >> 4, c4 = flat & 15;
            pb[i] = *(const float4*)(W + (size_t)(k0 + row) * HF + n0 + c4 * 4);
        }
    }

    for (int k0 = 0; k0 < IN_F; k0 += TK) {
        // write prefetched tiles to LDS
#pragma unroll
        for (int i = 0; i < 2; ++i) {
            int flat = i * 256 + t, row = flat >> 3, c4 = flat & 7;
            As[c4 * 4 + 0][row] = pa[i].x;
            As[c4 * 4 + 1][row] = pa[i].y;
            As[c4 * 4 + 2][row] = pa[i].z;
            As[c4 * 4 + 3][row] = pa[i].w;
        }
#pragma unroll
        for (int i = 0; i < 2; ++i) {
            int flat = i * 256 + t, row = flat >> 4, c4 = flat & 15;
            *(float4*)(&Bs[row][c4 * 4]) = pb[i];
        }
        __syncthreads();
        // issue next-tile loads (overlap with compute below)
        if (k0 + TK < IN_F) {
            int kn = k0 + TK;
#pragma unroll
            for (int i = 0; i < 2; ++i) {
                int flat = i * 256 + t, row = flat >> 3, c4 = flat & 7;
                pa[i] = *(const float4*)(x + (size_t)(m0 + row) * IN_F + kn + c4 * 4);
            }
#pragma unroll
            for (int i = 0; i < 2; ++i) {
                int flat = i * 256 + t, row = flat >> 4, c4 = flat & 15;
                pb[i] = *(const float4*)(W + (size_t)(kn + row) * HF + n0 + c4 * 4);
            }
        }
#pragma unroll
        for (int k = 0; k < TK; ++k) {
            float4 a4 = *(const float4*)(&As[k][ty * 4]);
            float4 b4 = *(const float4*)(&Bs[k][tx * 4]);
            float av[4] = {a4.x, a4.y, a4.z, a4.w};
            float bv[4] = {b4.x, b4.y, b4.z, b4.w};
#pragma unroll
            for (int ii = 0; ii < 4; ++ii)
#pragma unroll
                for (int jj = 0; jj < 4; ++jj)
                    acc[ii][jj] += av[ii] * bv[jj];
        }
        __syncthreads();
    }

    // write Whb (bf16, 8B per thread per row)
#pragma unroll
    for (int ii = 0; ii < 4; ++ii) {
        ushort4 v;
        v.x = f2b(acc[ii][0]);
        v.y = f2b(acc[ii][1]);
        v.z = f2b(acc[ii][2]);
        v.w = f2b(acc[ii][3]);
        *(ushort4*)(Whb + (size_t)(m0 + ty * 4 + ii) * HF + n0 + tx * 4) = v;
    }

    // ---- fused alpha epilogue (fp32-exact): tile covers head h fully ----
    int h = n0 >> 6;
    float a1v[4], a2v[4];
#pragma unroll
    for (int jj = 0; jj < 4; ++jj) {
        int f = tx * 4 + jj;
        a1v[jj] = a[f];
        a2v[jj] = a[OUT_F + f];
    }
#pragma unroll
    for (int ii = 0; ii < 4; ++ii) {
        float p1 = 0.f, p2 = 0.f;
#pragma unroll
        for (int jj = 0; jj < 4; ++jj) {
            p1 += acc[ii][jj] * a1v[jj];
            p2 += acc[ii][jj] * a2v[jj];
        }
#pragma unroll
        for (int mask = 1; mask < 16; mask <<= 1) {
            p1 += __shfl_xor(p1, mask);
            p2 += __shfl_xor(p2, mask);
        }
        if (tx == 0) {
            int node = m0 + ty * 4 + ii;
            asrc[node * HH + h] = p1;
            adst[node * HH + h] = p2;
        }
    }

    // ---- fused column-sum epilogue (fp32-exact) ----
    if (t < TN) Scol[t] = 0.f;
    __syncthreads();
#pragma unroll
    for (int jj = 0; jj < 4; ++jj) {
        float cs = acc[0][jj] + acc[1][jj] + acc[2][jj] + acc[3][jj];
        atomicAdd(&Scol[tx * 4 + jj], cs);
    }
    __syncthreads();
    if (t < TN) atomicAdd(&S[n0 + t], Scol[t]);
}

// ---------------------------------------------------------------------------
// K2: scatter edges into fixed-capacity CSR with exact dedup (bitmap atomicOr)
// AND compute per-edge attention weights w[h] = exp(leaky(as+ad)) - 1 for all
// 8 heads at insert time (hoisted out of the aggregate's critical path).
// ---------------------------------------------------------------------------
__global__ __launch_bounds__(256) void scatter_edges(const int* __restrict__ src,
                                                     const int* __restrict__ dst,
                                                     const float* __restrict__ asrc,
                                                     const float* __restrict__ adst,
                                                     unsigned int* __restrict__ bitmap,
                                                     int* __restrict__ cnt,
                                                     int* __restrict__ csr_dst,
                                                     float* __restrict__ csr_w) {
    int e = blockIdx.x * 256 + threadIdx.x;
    if (e >= EE) return;
    int s = src[e], d = dst[e];
    unsigned int bitidx = ((unsigned int)s << 12) | (unsigned int)d;
    unsigned int word   = bitidx >> 5;
    unsigned int mask   = 1u << (bitidx & 31);
    unsigned int old    = atomicOr(&bitmap[word], mask);
    if (!(old & mask)) {
        int pos  = atomicAdd(&cnt[s], 1);
        int slot = (s << 7) + pos;
        csr_dst[slot] = d;
        float4 s0 = *(const float4*)(asrc + s * HH);
        float4 s1 = *(const float4*)(asrc + s * HH + 4);
        float4 d0 = *(const float4*)(adst + d * HH);
        float4 d1 = *(const float4*)(adst + d * HH + 4);
        float ev[8] = {s0.x + d0.x, s0.y + d0.y, s0.z + d0.z, s0.w + d0.w,
                       s1.x + d1.x, s1.y + d1.y, s1.z + d1.z, s1.w + d1.w};
        float w[8];
#pragma unroll
        for (int h = 0; h < 8; ++h) {
            float x = ev[h];
            x = (x > 0.f) ? x : 0.2f * x;
            w[h] = __expf(x) - 1.f;
        }
        float4 w0 = {w[0], w[1], w[2], w[3]};
        float4 w1 = {w[4], w[5], w[6], w[7]};
        *(float4*)(csr_w + (size_t)slot * 8)     = w0;
        *(float4*)(csr_w + (size_t)slot * 8 + 4) = w1;
    }
}

// ---------------------------------------------------------------------------
// K3: per-node aggregation over bf16 Whb (4 MB table -> L2-resident gather).
// out[i,h,f] = (S[h,f] + sum_e w*Whb[m,h,f]) / (N + sum_e w)
// 512 threads = 4 groups x 128; lane covers 4 floats (8B bf16 load).
// Indices + weights staged in LDS; z from block-local LDS reduce.
// ---------------------------------------------------------------------------
__global__ __launch_bounds__(512) void aggregate_kernel(const unsigned short* __restrict__ Whb,
                                                        const float* __restrict__ S,
                                                        const int* __restrict__ cnt,
                                                        const int* __restrict__ csr_dst,
                                                        const float* __restrict__ csr_w,
                                                        float* __restrict__ out) {
    __shared__ float wbuf[CAP * HH];   // 4 KB (slot-major)
    __shared__ int   midx[CAP];        // 512 B
    __shared__ float red[4][HF];       // 8 KB
    __shared__ float denom[HH];
    int i = blockIdx.x;
    int t = threadIdx.x;               // 0..511
    int deg = cnt[i];

    const float* wrow = csr_w + ((size_t)i << 7) * HH;
    for (int idx = t; idx < deg * HH; idx += 512) wbuf[idx] = wrow[idx];
    if (t < deg) midx[t] = csr_dst[(i << 7) + t];
    __syncthreads();

    // per-head denominator: 8 heads x 16 lanes
    if (t < 128) {
        int h = t >> 4, ln = t & 15;
        float p = 0.f;
        for (int sl = ln; sl < deg; sl += 16) p += wbuf[sl * HH + h];
#pragma unroll
        for (int mask = 1; mask < 16; mask <<= 1) p += __shfl_xor(p, mask);
        if (ln == 0) denom[h] = (float)NN + p;
    }
    __syncthreads();

    int g = t >> 7;                    // edge group 0..3
    int r = t & 127;                   // covers floats r*4..r*4+3
    int h = r >> 4;
    float4 acc = {0.f, 0.f, 0.f, 0.f};

    // 1-deep software pipeline on the Whb gather
    int j = g;
    int   mC = 0; float wC = 0.f; uint2 uC = {0u, 0u};
    if (j < deg) {
        mC = midx[j];
        wC = wbuf[j * HH + h];
        uC = *(const uint2*)(Whb + ((size_t)mC << 9) + (r << 2));
    }
    while (j < deg) {
        int jn = j + 4;
        int   mN = 0; float wN = 0.f; uint2 uN = {0u, 0u};
        if (jn < deg) {
            mN = midx[jn];
            wN = wbuf[jn * HH + h];
            uN = *(const uint2*)(Whb + ((size_t)mN << 9) + (r << 2));
        }
        float v0 = b2f(uC.x & 0xFFFFu);
        float v1 = b2f(uC.x >> 16);
        float v2 = b2f(uC.y & 0xFFFFu);
        float v3 = b2f(uC.y >> 16);
        acc.x += wC * v0;
        acc.y += wC * v1;
        acc.z += wC * v2;
        acc.w += wC * v3;
        mC = mN; wC = wN; uC = uN;
        j = jn;
    }

    *(float4*)(&red[g][r << 2]) = acc;
    __syncthreads();

    float tot = red[0][t] + red[1][t] + red[2][t] + red[3][t] + S[t];
    out[((size_t)i << 9) + t] = tot / denom[t >> 6];
}

// ---------------------------------------------------------------------------
// launcher
// ---------------------------------------------------------------------------
extern "C" void kernel_launch(void* const* d_in, const int* in_sizes, int n_in,
                              void* d_out, int out_size, void* d_ws, size_t ws_size,
                              hipStream_t stream) {
    const float* x  = (const float*)d_in[0];
    const float* W  = (const float*)d_in[1];
    const float* a  = (const float*)d_in[2];
    const int*   ei = (const int*)d_in[3];
    const int* src = ei;
    const int* dst = ei + EE;
    float* out = (float*)d_out;

    // workspace layout (bytes)
    char* ws = (char*)d_ws;
    unsigned short* Whb = (unsigned short*)(ws + 0);      // 4096*512*2   = 4,194,304
    float* asrc     = (float*)(ws + 4194304);             // 131,072
    float* adst     = (float*)(ws + 4325376);             // 131,072
    int*   csr_dst  = (int*)  (ws + 4456448);             // 4096*128*4   = 2,097,152
    float* csr_w    = (float*)(ws + 6553600);             // 4096*128*8*4 = 16,777,216
    float* S        = (float*)(ws + 23330816);            // 2,048
    int*   cnt      = (int*)  (ws + 23332864);            // 16,384
    unsigned int* bitmap = (unsigned int*)(ws + 23349248);// 2,097,152

    // zero S + cnt + bitmap in one contiguous memset
    hipMemsetAsync(ws + 23330816, 0, 2048 + 16384 + 2097152, stream);

    // K1: fused GEMM (bf16 Wh out) + alphas + column sums
    gemm_fused<<<dim3(NN / TM, HF / TN), 256, 0, stream>>>(x, W, a, Whb, asrc, adst, S);

    // K2: CSR build with exact dedup + per-edge weights (all heads)
    scatter_edges<<<EE / 256, 256, 0, stream>>>(src, dst, asrc, adst, bitmap, cnt,
                                                csr_dst, csr_w);

    // K3: aggregation (bf16 gather, L2-resident)
    aggregate_kernel<<<NN, 512, 0, stream>>>(Whb, S, cnt, csr_dst, csr_w, out);
}